// Round 4
// baseline (245.382 us; speedup 1.0000x reference)
//
#include <hip/hip_runtime.h>

#define N_KSV 37248
#define N_KW  36864
#define KSPLIT 32
#define CHUNK 48

typedef float f32x4 __attribute__((ext_vector_type(4)));
typedef float f32x2 __attribute__((ext_vector_type(2)));
typedef short short8 __attribute__((ext_vector_type(8)));
typedef short short4v __attribute__((ext_vector_type(4)));
typedef __bf16 bf16x8 __attribute__((ext_vector_type(8)));

__device__ inline short f2bs(float f) {
  unsigned u = __builtin_bit_cast(unsigned, f);
  u += 0x7fffu + ((u >> 16) & 1u);
  return (short)(u >> 16);
}

__device__ inline float bs2f(short s) {
  unsigned u = ((unsigned)(unsigned short)s) << 16;
  return __builtin_bit_cast(float, u);
}

__device__ inline f32x4 mfma16(short8 a, short8 b, f32x4 c) {
  return __builtin_amdgcn_mfma_f32_16x16x32_bf16(
      __builtin_bit_cast(bf16x8, a), __builtin_bit_cast(bf16x8, b), c, 0, 0, 0);
}

// ---------------- hypernet small chain (fp32) ----------------
__global__ void k_h0(const float* __restrict__ lat, const float* __restrict__ w,
                     const float* __restrict__ bias, float* __restrict__ h0) {
  int j = blockIdx.x * 256 + threadIdx.x;   // < 512
  int b = blockIdx.y;
  const float* lp = lat + b * 512;
  float acc = bias[j];
#pragma unroll 16
  for (int k = 0; k < 512; ++k) acc = fmaf(lp[k], w[k * 512 + j], acc);
  h0[b * 512 + j] = acc;
}

__global__ void k_t1(const float* __restrict__ h0, const float* __restrict__ w,
                     const float* __restrict__ bias, float* __restrict__ t1) {
  int j = blockIdx.x * 256 + threadIdx.x;   // < 1024
  int b = blockIdx.y;
  const float* hp = h0 + b * 512;
  float acc = bias[j];
#pragma unroll 16
  for (int k = 0; k < 512; ++k) acc = fmaf(hp[k], w[k * 1024 + j], acc);
  t1[b * 1024 + j] = fmaxf(acc, 0.f);
}

__global__ void k_h(const float* __restrict__ h0, const float* __restrict__ t1,
                    const float* __restrict__ w, const float* __restrict__ bias,
                    float* __restrict__ h, float* __restrict__ hx) {
  int j = blockIdx.x * 256 + threadIdx.x;   // < 512
  int b = blockIdx.y;
  const float* tp = t1 + b * 1024;
  float acc = bias[j];
#pragma unroll 16
  for (int k = 0; k < 1024; ++k) acc = fmaf(tp[k], w[k * 512 + j], acc);
  float v = acc + h0[b * 512 + j];
  h[b * 512 + j] = v;
  hx[j * 16 + b] = v;   // rows 0..511 of combined [1536][16]
}

__global__ void k_t2(const float* __restrict__ h, const float* __restrict__ w,
                     const float* __restrict__ bias, float* __restrict__ hx) {
  int j = blockIdx.x * 256 + threadIdx.x;   // < 1024
  int b = blockIdx.y;
  const float* hp = h + b * 512;
  float acc = bias[j];
#pragma unroll 16
  for (int k = 0; k < 512; ++k) acc = fmaf(hp[k], w[k * 1024 + j], acc);
  hx[(512 + j) * 16 + b] = fmaxf(acc, 0.f);  // rows 512..1535
}

// ---------------- fat GEMM: ksv = h @ l2_ws + t2 @ l2_w2 (k-split partials) ----------------
// 4 columns/thread (16B dwordx4 weight loads, 64B in flight at unroll 4);
// occupancy kept high via KSPLIT=32 (grid 37x32 = 1184 blocks, ~18.5 waves/CU).
// h-slice staged in LDS, broadcast-read. Partials stored as bf16 (halves k6 traffic).
__global__ __launch_bounds__(256) void k5_partial(
    const float* __restrict__ wsm, const float* __restrict__ w2,
    const float* __restrict__ hx, short* __restrict__ part) {
  __shared__ float hs[CHUNK * 16];
  const int tid = threadIdx.x;
  const int chunk = blockIdx.y;
  const int k0 = chunk * CHUNK, k1 = k0 + CHUNK;

  // stage hx[k0..k1) -> LDS (coalesced float4)
  {
    const f32x4* src = reinterpret_cast<const f32x4*>(hx + (size_t)k0 * 16);
    f32x4* dst = reinterpret_cast<f32x4*>(hs);
    for (int idx = tid; idx < CHUNK * 4; idx += 256) dst[idx] = src[idx];
  }
  __syncthreads();

  const int j0 = (blockIdx.x * 256 + tid) * 4;
  if (j0 >= N_KSV) return;

  f32x4 acc[16];
#pragma unroll
  for (int b = 0; b < 16; ++b) acc[b] = (f32x4){0.f, 0.f, 0.f, 0.f};

  const int ka1 = k1 < 512 ? k1 : 512;
#pragma unroll 4
  for (int kk = k0; kk < ka1; ++kk) {
    f32x4 wv = *reinterpret_cast<const f32x4*>(wsm + (size_t)kk * N_KSV + j0);
    const f32x4* hp = reinterpret_cast<const f32x4*>(hs + (kk - k0) * 16);
    f32x4 h0v = hp[0], h1v = hp[1], h2v = hp[2], h3v = hp[3];
#pragma unroll
    for (int q = 0; q < 4; ++q) {
      acc[q]      += h0v[q] * wv;
      acc[4 + q]  += h1v[q] * wv;
      acc[8 + q]  += h2v[q] * wv;
      acc[12 + q] += h3v[q] * wv;
    }
  }
  const int kb0 = k0 > 512 ? k0 : 512;
#pragma unroll 4
  for (int kk = kb0; kk < k1; ++kk) {
    f32x4 wv = *reinterpret_cast<const f32x4*>(w2 + (size_t)(kk - 512) * N_KSV + j0);
    const f32x4* hp = reinterpret_cast<const f32x4*>(hs + (kk - k0) * 16);
    f32x4 h0v = hp[0], h1v = hp[1], h2v = hp[2], h3v = hp[3];
#pragma unroll
    for (int q = 0; q < 4; ++q) {
      acc[q]      += h0v[q] * wv;
      acc[4 + q]  += h1v[q] * wv;
      acc[8 + q]  += h2v[q] * wv;
      acc[12 + q] += h3v[q] * wv;
    }
  }

  short* pp = part + (size_t)chunk * 16 * N_KSV + j0;
#pragma unroll
  for (int b = 0; b < 16; ++b) {
    short4v sv;
#pragma unroll
    for (int q = 0; q < 4; ++q) sv[q] = f2bs(acc[b][q]);
    *reinterpret_cast<short4v*>(pp + (size_t)b * N_KSV) = sv;
  }
}

__global__ void k6_reduce(const short* __restrict__ part, const float* __restrict__ b2,
                          float* __restrict__ ksv, short* __restrict__ kwb) {
  int j0 = (blockIdx.x * 256 + threadIdx.x) * 4;
  if (j0 >= N_KSV) return;
  int b = blockIdx.y;
  f32x4 s = *reinterpret_cast<const f32x4*>(b2 + j0);
#pragma unroll 4
  for (int c = 0; c < KSPLIT; ++c) {
    short4v pv = *reinterpret_cast<const short4v*>(part + (size_t)(c * 16 + b) * N_KSV + j0);
#pragma unroll
    for (int q = 0; q < 4; ++q) s[q] += bs2f(pv[q]);
  }
  *reinterpret_cast<f32x4*>(ksv + (size_t)b * N_KSV + j0) = s;
  if (j0 < N_KW) {
    short4v sv;
#pragma unroll
    for (int q = 0; q < 4; ++q) sv[q] = f2bs(s[q]);
    *reinterpret_cast<short4v*>(kwb + (size_t)b * N_KW + j0) = sv;
  }
}

// ---------------- fused dyna block: 4 x (1x1 conv) via bf16 MFMA ----------------
__device__ inline int xT_idx(int p, int c) {
  return p * 64 + ((((c >> 3) ^ (p & 7)) << 3) | (c & 7));
}
__device__ inline int h_idx(int p, int c) {
  return p * 128 + ((((c >> 3) ^ (p & 7)) << 3) | (c & 7));
}

__global__ __launch_bounds__(256) void k_dyna(const float* __restrict__ x,
                                              const short* __restrict__ kwb,
                                              const float* __restrict__ ksv,
                                              float* __restrict__ out) {
  __shared__ __align__(16) short lds[20480];  // xT:0..4095  h1:4096..12287  h2:12288..20479
  short* xT = lds;
  short* h1 = lds + 4096;
  short* h2 = lds + 12288;

  const int tid = threadIdx.x;
  const int lane = tid & 63;
  const int w = tid >> 6;        // wave 0..3
  const int l15 = lane & 15;
  const int lg = lane >> 4;      // 0..3

  const int b = blockIdx.x >> 8;
  const int pos0 = (blockIdx.x & 255) << 6;

  const float* xb = x + ((size_t)b << 20) + pos0;           // x[b][.][pos0+.]
  const short* kw = kwb + b * N_KW;
  const float* bias = ksv + (size_t)b * N_KSV + N_KW;       // b_in | b_mid | b_out | b_sh

  // ---- stage x tile -> xT (bf16, transposed, swizzled) ----
#pragma unroll
  for (int i = 0; i < 8; ++i) {
    int p = lane;
    int cp = i * 4 + w;          // 0..31
    int c = cp * 2;
    float v0 = xb[(size_t)c * 16384 + p];
    float v1 = xb[(size_t)(c + 1) * 16384 + p];
    int idx = xT_idx(p, c);      // even; packs c, c+1
    int pk = (int)(unsigned short)f2bs(v0) | ((int)f2bs(v1) << 16);
    *reinterpret_cast<int*>(&xT[idx]) = pk;
  }
  __syncthreads();

  // ---- layer 1: h1 = relu(Kin(128x64) @ x + b_in) ----
  short8 a1[2][2];
#pragma unroll
  for (int mt = 0; mt < 2; ++mt)
#pragma unroll
    for (int kf = 0; kf < 2; ++kf)
      a1[mt][kf] = *reinterpret_cast<const short8*>(
          kw + (w * 32 + mt * 16 + l15) * 64 + kf * 32 + lg * 8);

  f32x4 zero = {0.f, 0.f, 0.f, 0.f};
  f32x4 acc1[2][4];
#pragma unroll
  for (int mt = 0; mt < 2; ++mt)
#pragma unroll
    for (int nt = 0; nt < 4; ++nt) acc1[mt][nt] = zero;

#pragma unroll
  for (int nt = 0; nt < 4; ++nt) {
    int p = nt * 16 + l15;
    short8 b0 = *reinterpret_cast<const short8*>(&xT[xT_idx(p, lg * 8)]);
    short8 b1 = *reinterpret_cast<const short8*>(&xT[xT_idx(p, 32 + lg * 8)]);
#pragma unroll
    for (int mt = 0; mt < 2; ++mt) {
      acc1[mt][nt] = mfma16(a1[mt][0], b0, acc1[mt][nt]);
      acc1[mt][nt] = mfma16(a1[mt][1], b1, acc1[mt][nt]);
    }
  }
#pragma unroll
  for (int mt = 0; mt < 2; ++mt) {
    int ch0 = w * 32 + mt * 16 + lg * 4;
    f32x4 bv = *reinterpret_cast<const f32x4*>(bias + ch0);
#pragma unroll
    for (int nt = 0; nt < 4; ++nt) {
      int p = nt * 16 + l15;
      short4v hv;
#pragma unroll
      for (int jj = 0; jj < 4; ++jj)
        hv[jj] = f2bs(fmaxf(acc1[mt][nt][jj] + bv[jj], 0.f));
      *reinterpret_cast<short4v*>(&h1[h_idx(p, ch0)]) = hv;
    }
  }
  __syncthreads();

  // ---- layer 2: h2 = relu(Kmid(128x128) @ h1 + b_mid) ----
  short8 a2[2][4];
#pragma unroll
  for (int mt = 0; mt < 2; ++mt)
#pragma unroll
    for (int kf = 0; kf < 4; ++kf)
      a2[mt][kf] = *reinterpret_cast<const short8*>(
          kw + 8192 + (w * 32 + mt * 16 + l15) * 128 + kf * 32 + lg * 8);

  f32x4 acc2[2][4];
#pragma unroll
  for (int mt = 0; mt < 2; ++mt)
#pragma unroll
    for (int nt = 0; nt < 4; ++nt) acc2[mt][nt] = zero;

#pragma unroll
  for (int nt = 0; nt < 4; ++nt) {
    int p = nt * 16 + l15;
    short8 bb[4];
#pragma unroll
    for (int kf = 0; kf < 4; ++kf)
      bb[kf] = *reinterpret_cast<const short8*>(&h1[h_idx(p, kf * 32 + lg * 8)]);
#pragma unroll
    for (int mt = 0; mt < 2; ++mt)
#pragma unroll
      for (int kf = 0; kf < 4; ++kf)
        acc2[mt][nt] = mfma16(a2[mt][kf], bb[kf], acc2[mt][nt]);
  }
#pragma unroll
  for (int mt = 0; mt < 2; ++mt) {
    int ch0 = w * 32 + mt * 16 + lg * 4;
    f32x4 bv = *reinterpret_cast<const f32x4*>(bias + 128 + ch0);
#pragma unroll
    for (int nt = 0; nt < 4; ++nt) {
      int p = nt * 16 + l15;
      short4v hv;
#pragma unroll
      for (int jj = 0; jj < 4; ++jj)
        hv[jj] = f2bs(fmaxf(acc2[mt][nt][jj] + bv[jj], 0.f));
      *reinterpret_cast<short4v*>(&h2[h_idx(p, ch0)]) = hv;
    }
  }
  __syncthreads();

  // ---- layer 3: out = Kout(64x128) @ h2 + Ksh(64x64) @ x + b_out + b_sh ----
  short8 a3[4], ash[2];
#pragma unroll
  for (int kf = 0; kf < 4; ++kf)
    a3[kf] = *reinterpret_cast<const short8*>(
        kw + 24576 + (w * 16 + l15) * 128 + kf * 32 + lg * 8);
#pragma unroll
  for (int kf = 0; kf < 2; ++kf)
    ash[kf] = *reinterpret_cast<const short8*>(
        kw + 32768 + (w * 16 + l15) * 64 + kf * 32 + lg * 8);

  int ch0 = w * 16 + lg * 4;
  f32x4 bo = *reinterpret_cast<const f32x4*>(bias + 256 + ch0);
  f32x4 bs = *reinterpret_cast<const f32x4*>(bias + 320 + ch0);

#pragma unroll
  for (int nt = 0; nt < 4; ++nt) {
    int p = nt * 16 + l15;
    f32x4 acc = zero;
#pragma unroll
    for (int kf = 0; kf < 4; ++kf) {
      short8 bb = *reinterpret_cast<const short8*>(&h2[h_idx(p, kf * 32 + lg * 8)]);
      acc = mfma16(a3[kf], bb, acc);
    }
#pragma unroll
    for (int kf = 0; kf < 2; ++kf) {
      short8 bb = *reinterpret_cast<const short8*>(&xT[xT_idx(p, kf * 32 + lg * 8)]);
      acc = mfma16(ash[kf], bb, acc);
    }
#pragma unroll
    for (int jj = 0; jj < 4; ++jj)
      out[((size_t)(b * 64 + ch0 + jj) << 14) + pos0 + p] = acc[jj] + bo[jj] + bs[jj];
  }
}

extern "C" void kernel_launch(void* const* d_in, const int* in_sizes, int n_in,
                              void* d_out, int out_size, void* d_ws, size_t ws_size,
                              hipStream_t stream) {
  const float* x    = (const float*)d_in[0];
  const float* lat  = (const float*)d_in[1];
  const float* dk_w = (const float*)d_in[2];
  const float* dk_b = (const float*)d_in[3];
  const float* l1w1 = (const float*)d_in[4];
  const float* l1b1 = (const float*)d_in[5];
  const float* l1w2 = (const float*)d_in[6];
  const float* l1b2 = (const float*)d_in[7];
  const float* l2w1 = (const float*)d_in[8];
  const float* l2b1 = (const float*)d_in[9];
  const float* l2w2 = (const float*)d_in[10];
  const float* l2b2 = (const float*)d_in[11];
  const float* l2ws = (const float*)d_in[12];
  float* out = (float*)d_out;
  float* wsf = (float*)d_ws;

  float* h0  = wsf;                  // 8192
  float* t1  = wsf + 8192;           // 16384
  float* h   = wsf + 24576;          // 8192
  float* hx  = wsf + 32768;          // 24576  ([1536][16] combined h|t2)
  float* ksv = wsf + 57344;          // 595968
  short* part = (short*)(wsf + 653312);          // KSPLIT*16*N_KSV bf16
  short* kwb  = part + (size_t)KSPLIT * 16 * N_KSV;

  k_h0<<<dim3(2, 16), 256, 0, stream>>>(lat, dk_w, dk_b, h0);
  k_t1<<<dim3(4, 16), 256, 0, stream>>>(h0, l1w1, l1b1, t1);
  k_h <<<dim3(2, 16), 256, 0, stream>>>(h0, t1, l1w2, l1b2, h, hx);
  k_t2<<<dim3(4, 16), 256, 0, stream>>>(h, l2w1, l2b1, hx);
  k5_partial<<<dim3((N_KSV / 4 + 255) / 256, KSPLIT), 256, 0, stream>>>(l2ws, l2w2, hx, part);
  k6_reduce<<<dim3((N_KSV / 4 + 255) / 256, 16), 256, 0, stream>>>(part, l2b2, ksv, kwb);
  k_dyna<<<dim3(4096), 256, 0, stream>>>(x, kwb, ksv, out);
}

// Round 5
// 230.830 us; speedup vs baseline: 1.0630x; 1.0630x over previous
//
#include <hip/hip_runtime.h>

#define N_KSV 37248
#define N_KW  36864
#define KSPLIT 32
#define CHUNK 48

typedef float f32x4 __attribute__((ext_vector_type(4)));
typedef float f32x2 __attribute__((ext_vector_type(2)));
typedef short short8 __attribute__((ext_vector_type(8)));
typedef short short4v __attribute__((ext_vector_type(4)));
typedef __bf16 bf16x8 __attribute__((ext_vector_type(8)));

__device__ inline short f2bs(float f) {
  unsigned u = __builtin_bit_cast(unsigned, f);
  u += 0x7fffu + ((u >> 16) & 1u);
  return (short)(u >> 16);
}

__device__ inline float bs2f(short s) {
  unsigned u = ((unsigned)(unsigned short)s) << 16;
  return __builtin_bit_cast(float, u);
}

__device__ inline f32x4 mfma16(short8 a, short8 b, f32x4 c) {
  return __builtin_amdgcn_mfma_f32_16x16x32_bf16(
      __builtin_bit_cast(bf16x8, a), __builtin_bit_cast(bf16x8, b), c, 0, 0, 0);
}

// ---------------- hypernet small chain (fp32) ----------------
__global__ void k_h0(const float* __restrict__ lat, const float* __restrict__ w,
                     const float* __restrict__ bias, float* __restrict__ h0) {
  int j = blockIdx.x * 256 + threadIdx.x;   // < 512
  int b = blockIdx.y;
  const float* lp = lat + b * 512;
  float acc = bias[j];
#pragma unroll 16
  for (int k = 0; k < 512; ++k) acc = fmaf(lp[k], w[k * 512 + j], acc);
  h0[b * 512 + j] = acc;
}

__global__ void k_t1(const float* __restrict__ h0, const float* __restrict__ w,
                     const float* __restrict__ bias, float* __restrict__ t1) {
  int j = blockIdx.x * 256 + threadIdx.x;   // < 1024
  int b = blockIdx.y;
  const float* hp = h0 + b * 512;
  float acc = bias[j];
#pragma unroll 16
  for (int k = 0; k < 512; ++k) acc = fmaf(hp[k], w[k * 1024 + j], acc);
  t1[b * 1024 + j] = fmaxf(acc, 0.f);
}

__global__ void k_h(const float* __restrict__ h0, const float* __restrict__ t1,
                    const float* __restrict__ w, const float* __restrict__ bias,
                    float* __restrict__ h, float* __restrict__ hx) {
  int j = blockIdx.x * 256 + threadIdx.x;   // < 512
  int b = blockIdx.y;
  const float* tp = t1 + b * 1024;
  float acc = bias[j];
#pragma unroll 16
  for (int k = 0; k < 1024; ++k) acc = fmaf(tp[k], w[k * 512 + j], acc);
  float v = acc + h0[b * 512 + j];
  h[b * 512 + j] = v;
  hx[j * 16 + b] = v;   // rows 0..511 of combined [1536][16]
}

__global__ void k_t2(const float* __restrict__ h, const float* __restrict__ w,
                     const float* __restrict__ bias, float* __restrict__ hx) {
  int j = blockIdx.x * 256 + threadIdx.x;   // < 1024
  int b = blockIdx.y;
  const float* hp = h + b * 512;
  float acc = bias[j];
#pragma unroll 16
  for (int k = 0; k < 512; ++k) acc = fmaf(hp[k], w[k * 1024 + j], acc);
  hx[(512 + j) * 16 + b] = fmaxf(acc, 0.f);  // rows 512..1535
}

// ---------------- fat GEMM: ksv = h @ l2_ws + t2 @ l2_w2 (k-split partials) ----------------
// Latency-bound regime: maximize waves (2336 blocks, ~32 waves/CU) and keep
// 4-8 weight loads in flight per wave via explicit double-buffered prefetch.
#define KSTEP(kt, wv) { \
    const f32x4* hp_ = reinterpret_cast<const f32x4*>(hs + (kt) * 16); \
    f32x4 h0v = hp_[0], h1v = hp_[1], h2v = hp_[2], h3v = hp_[3]; \
    _Pragma("unroll") \
    for (int q = 0; q < 4; ++q) { \
      acc[q]      += h0v[q] * (wv); \
      acc[4 + q]  += h1v[q] * (wv); \
      acc[8 + q]  += h2v[q] * (wv); \
      acc[12 + q] += h3v[q] * (wv); \
    } }

__global__ __launch_bounds__(256) void k5_partial(
    const float* __restrict__ wsm, const float* __restrict__ w2,
    const float* __restrict__ hx, short* __restrict__ part) {
  __shared__ float hs[CHUNK * 16];
  const int tid = threadIdx.x;
  const int chunk = blockIdx.y;
  const int k0 = chunk * CHUNK;

  // stage hx[k0..k0+CHUNK) -> LDS (coalesced float4; broadcast-read later)
  {
    const f32x4* src = reinterpret_cast<const f32x4*>(hx + (size_t)k0 * 16);
    f32x4* dst = reinterpret_cast<f32x4*>(hs);
    for (int idx = tid; idx < CHUNK * 4; idx += 256) dst[idx] = src[idx];
  }
  __syncthreads();

  const int j0 = (blockIdx.x * 256 + tid) * 2;
  if (j0 >= N_KSV) return;

  f32x2 acc[16];
#pragma unroll
  for (int b = 0; b < 16; ++b) acc[b] = (f32x2){0.f, 0.f};

  // uniform weight-row pointer for global k (clamped: prefetch overrun safe)
  auto wptr = [&](int kk) -> const f32x2* {
    kk = kk < 1535 ? kk : 1535;
    const float* base = (kk < 512) ? (wsm + (size_t)kk * N_KSV)
                                   : (w2 + (size_t)(kk - 512) * N_KSV);
    return reinterpret_cast<const f32x2*>(base + j0);
  };

  f32x2 wA0 = *wptr(k0 + 0), wA1 = *wptr(k0 + 1);
  f32x2 wA2 = *wptr(k0 + 2), wA3 = *wptr(k0 + 3);
  f32x2 wB0, wB1, wB2, wB3;

#pragma unroll
  for (int kt = 0; kt < CHUNK; kt += 8) {
    wB0 = *wptr(k0 + kt + 4); wB1 = *wptr(k0 + kt + 5);
    wB2 = *wptr(k0 + kt + 6); wB3 = *wptr(k0 + kt + 7);
    KSTEP(kt + 0, wA0) KSTEP(kt + 1, wA1) KSTEP(kt + 2, wA2) KSTEP(kt + 3, wA3)
    wA0 = *wptr(k0 + kt + 8); wA1 = *wptr(k0 + kt + 9);
    wA2 = *wptr(k0 + kt + 10); wA3 = *wptr(k0 + kt + 11);
    KSTEP(kt + 4, wB0) KSTEP(kt + 5, wB1) KSTEP(kt + 6, wB2) KSTEP(kt + 7, wB3)
  }

  short* pp = part + (size_t)chunk * 16 * N_KSV + j0;
#pragma unroll
  for (int b = 0; b < 16; ++b) {
    int pk = (int)(unsigned short)f2bs(acc[b][0]) | ((int)f2bs(acc[b][1]) << 16);
    *reinterpret_cast<int*>(pp + (size_t)b * N_KSV) = pk;
  }
}

__global__ void k6_reduce(const short* __restrict__ part, const float* __restrict__ b2,
                          float* __restrict__ ksv, short* __restrict__ kwb) {
  int j0 = (blockIdx.x * 256 + threadIdx.x) * 4;
  if (j0 >= N_KSV) return;
  int b = blockIdx.y;
  f32x4 s = *reinterpret_cast<const f32x4*>(b2 + j0);
#pragma unroll 4
  for (int c = 0; c < KSPLIT; ++c) {
    short4v pv = *reinterpret_cast<const short4v*>(part + (size_t)(c * 16 + b) * N_KSV + j0);
#pragma unroll
    for (int q = 0; q < 4; ++q) s[q] += bs2f(pv[q]);
  }
  *reinterpret_cast<f32x4*>(ksv + (size_t)b * N_KSV + j0) = s;
  if (j0 < N_KW) {
    short4v sv;
#pragma unroll
    for (int q = 0; q < 4; ++q) sv[q] = f2bs(s[q]);
    *reinterpret_cast<short4v*>(kwb + (size_t)b * N_KW + j0) = sv;
  }
}

// ---------------- fused dyna block: 4 x (1x1 conv) via bf16 MFMA ----------------
__device__ inline int xT_idx(int p, int c) {
  return p * 64 + ((((c >> 3) ^ (p & 7)) << 3) | (c & 7));
}
__device__ inline int h_idx(int p, int c) {
  return p * 128 + ((((c >> 3) ^ (p & 7)) << 3) | (c & 7));
}

__global__ __launch_bounds__(256) void k_dyna(const float* __restrict__ x,
                                              const short* __restrict__ kwb,
                                              const float* __restrict__ ksv,
                                              float* __restrict__ out) {
  __shared__ __align__(16) short lds[20480];  // xT:0..4095  h1:4096..12287  h2:12288..20479
  short* xT = lds;
  short* h1 = lds + 4096;
  short* h2 = lds + 12288;

  const int tid = threadIdx.x;
  const int lane = tid & 63;
  const int w = tid >> 6;        // wave 0..3
  const int l15 = lane & 15;
  const int lg = lane >> 4;      // 0..3

  const int b = blockIdx.x >> 8;
  const int pos0 = (blockIdx.x & 255) << 6;

  const float* xb = x + ((size_t)b << 20) + pos0;           // x[b][.][pos0+.]
  const short* kw = kwb + b * N_KW;
  const float* bias = ksv + (size_t)b * N_KSV + N_KW;       // b_in | b_mid | b_out | b_sh

  // ---- stage x tile -> xT (bf16, transposed, swizzled) ----
#pragma unroll
  for (int i = 0; i < 8; ++i) {
    int p = lane;
    int cp = i * 4 + w;          // 0..31
    int c = cp * 2;
    float v0 = xb[(size_t)c * 16384 + p];
    float v1 = xb[(size_t)(c + 1) * 16384 + p];
    int idx = xT_idx(p, c);      // even; packs c, c+1
    int pk = (int)(unsigned short)f2bs(v0) | ((int)f2bs(v1) << 16);
    *reinterpret_cast<int*>(&xT[idx]) = pk;
  }
  __syncthreads();

  // ---- layer 1: h1 = relu(Kin(128x64) @ x + b_in) ----
  short8 a1[2][2];
#pragma unroll
  for (int mt = 0; mt < 2; ++mt)
#pragma unroll
    for (int kf = 0; kf < 2; ++kf)
      a1[mt][kf] = *reinterpret_cast<const short8*>(
          kw + (w * 32 + mt * 16 + l15) * 64 + kf * 32 + lg * 8);

  f32x4 zero = {0.f, 0.f, 0.f, 0.f};
  f32x4 acc1[2][4];
#pragma unroll
  for (int mt = 0; mt < 2; ++mt)
#pragma unroll
    for (int nt = 0; nt < 4; ++nt) acc1[mt][nt] = zero;

#pragma unroll
  for (int nt = 0; nt < 4; ++nt) {
    int p = nt * 16 + l15;
    short8 b0 = *reinterpret_cast<const short8*>(&xT[xT_idx(p, lg * 8)]);
    short8 b1 = *reinterpret_cast<const short8*>(&xT[xT_idx(p, 32 + lg * 8)]);
#pragma unroll
    for (int mt = 0; mt < 2; ++mt) {
      acc1[mt][nt] = mfma16(a1[mt][0], b0, acc1[mt][nt]);
      acc1[mt][nt] = mfma16(a1[mt][1], b1, acc1[mt][nt]);
    }
  }
#pragma unroll
  for (int mt = 0; mt < 2; ++mt) {
    int ch0 = w * 32 + mt * 16 + lg * 4;
    f32x4 bv = *reinterpret_cast<const f32x4*>(bias + ch0);
#pragma unroll
    for (int nt = 0; nt < 4; ++nt) {
      int p = nt * 16 + l15;
      short4v hv;
#pragma unroll
      for (int jj = 0; jj < 4; ++jj)
        hv[jj] = f2bs(fmaxf(acc1[mt][nt][jj] + bv[jj], 0.f));
      *reinterpret_cast<short4v*>(&h1[h_idx(p, ch0)]) = hv;
    }
  }
  __syncthreads();

  // ---- layer 2: h2 = relu(Kmid(128x128) @ h1 + b_mid) ----
  short8 a2[2][4];
#pragma unroll
  for (int mt = 0; mt < 2; ++mt)
#pragma unroll
    for (int kf = 0; kf < 4; ++kf)
      a2[mt][kf] = *reinterpret_cast<const short8*>(
          kw + 8192 + (w * 32 + mt * 16 + l15) * 128 + kf * 32 + lg * 8);

  f32x4 acc2[2][4];
#pragma unroll
  for (int mt = 0; mt < 2; ++mt)
#pragma unroll
    for (int nt = 0; nt < 4; ++nt) acc2[mt][nt] = zero;

#pragma unroll
  for (int nt = 0; nt < 4; ++nt) {
    int p = nt * 16 + l15;
    short8 bb[4];
#pragma unroll
    for (int kf = 0; kf < 4; ++kf)
      bb[kf] = *reinterpret_cast<const short8*>(&h1[h_idx(p, kf * 32 + lg * 8)]);
#pragma unroll
    for (int mt = 0; mt < 2; ++mt)
#pragma unroll
      for (int kf = 0; kf < 4; ++kf)
        acc2[mt][nt] = mfma16(a2[mt][kf], bb[kf], acc2[mt][nt]);
  }
#pragma unroll
  for (int mt = 0; mt < 2; ++mt) {
    int ch0 = w * 32 + mt * 16 + lg * 4;
    f32x4 bv = *reinterpret_cast<const f32x4*>(bias + 128 + ch0);
#pragma unroll
    for (int nt = 0; nt < 4; ++nt) {
      int p = nt * 16 + l15;
      short4v hv;
#pragma unroll
      for (int jj = 0; jj < 4; ++jj)
        hv[jj] = f2bs(fmaxf(acc2[mt][nt][jj] + bv[jj], 0.f));
      *reinterpret_cast<short4v*>(&h2[h_idx(p, ch0)]) = hv;
    }
  }
  __syncthreads();

  // ---- layer 3: out = Kout(64x128) @ h2 + Ksh(64x64) @ x + b_out + b_sh ----
  short8 a3[4], ash[2];
#pragma unroll
  for (int kf = 0; kf < 4; ++kf)
    a3[kf] = *reinterpret_cast<const short8*>(
        kw + 24576 + (w * 16 + l15) * 128 + kf * 32 + lg * 8);
#pragma unroll
  for (int kf = 0; kf < 2; ++kf)
    ash[kf] = *reinterpret_cast<const short8*>(
        kw + 32768 + (w * 16 + l15) * 64 + kf * 32 + lg * 8);

  int ch0 = w * 16 + lg * 4;
  f32x4 bo = *reinterpret_cast<const f32x4*>(bias + 256 + ch0);
  f32x4 bs = *reinterpret_cast<const f32x4*>(bias + 320 + ch0);

#pragma unroll
  for (int nt = 0; nt < 4; ++nt) {
    int p = nt * 16 + l15;
    f32x4 acc = zero;
#pragma unroll
    for (int kf = 0; kf < 4; ++kf) {
      short8 bb = *reinterpret_cast<const short8*>(&h2[h_idx(p, kf * 32 + lg * 8)]);
      acc = mfma16(a3[kf], bb, acc);
    }
#pragma unroll
    for (int kf = 0; kf < 2; ++kf) {
      short8 bb = *reinterpret_cast<const short8*>(&xT[xT_idx(p, kf * 32 + lg * 8)]);
      acc = mfma16(ash[kf], bb, acc);
    }
#pragma unroll
    for (int jj = 0; jj < 4; ++jj)
      out[((size_t)(b * 64 + ch0 + jj) << 14) + pos0 + p] = acc[jj] + bo[jj] + bs[jj];
  }
}

extern "C" void kernel_launch(void* const* d_in, const int* in_sizes, int n_in,
                              void* d_out, int out_size, void* d_ws, size_t ws_size,
                              hipStream_t stream) {
  const float* x    = (const float*)d_in[0];
  const float* lat  = (const float*)d_in[1];
  const float* dk_w = (const float*)d_in[2];
  const float* dk_b = (const float*)d_in[3];
  const float* l1w1 = (const float*)d_in[4];
  const float* l1b1 = (const float*)d_in[5];
  const float* l1w2 = (const float*)d_in[6];
  const float* l1b2 = (const float*)d_in[7];
  const float* l2w1 = (const float*)d_in[8];
  const float* l2b1 = (const float*)d_in[9];
  const float* l2w2 = (const float*)d_in[10];
  const float* l2b2 = (const float*)d_in[11];
  const float* l2ws = (const float*)d_in[12];
  float* out = (float*)d_out;
  float* wsf = (float*)d_ws;

  float* h0  = wsf;                  // 8192
  float* t1  = wsf + 8192;           // 16384
  float* h   = wsf + 24576;          // 8192
  float* hx  = wsf + 32768;          // 24576  ([1536][16] combined h|t2)
  float* ksv = wsf + 57344;          // 595968
  short* part = (short*)(wsf + 653312);          // KSPLIT*16*N_KSV bf16
  short* kwb  = part + (size_t)KSPLIT * 16 * N_KSV;

  k_h0<<<dim3(2, 16), 256, 0, stream>>>(lat, dk_w, dk_b, h0);
  k_t1<<<dim3(4, 16), 256, 0, stream>>>(h0, l1w1, l1b1, t1);
  k_h <<<dim3(2, 16), 256, 0, stream>>>(h0, t1, l1w2, l1b2, h, hx);
  k_t2<<<dim3(4, 16), 256, 0, stream>>>(h, l2w1, l2b1, hx);
  k5_partial<<<dim3((N_KSV / 2 + 255) / 256, KSPLIT), 256, 0, stream>>>(l2ws, l2w2, hx, part);
  k6_reduce<<<dim3((N_KSV / 4 + 255) / 256, 16), 256, 0, stream>>>(part, l2b2, ksv, kwb);
  k_dyna<<<dim3(4096), 256, 0, stream>>>(x, kwb, ksv, out);
}

// Round 6
// 228.466 us; speedup vs baseline: 1.0740x; 1.0103x over previous
//
#include <hip/hip_runtime.h>

#define N_KSV 37248
#define N_KW  36864
#define KSPLIT 24
#define CHUNK 64

typedef float f32x4 __attribute__((ext_vector_type(4)));
typedef float f32x2 __attribute__((ext_vector_type(2)));
typedef short short8 __attribute__((ext_vector_type(8)));
typedef short short4v __attribute__((ext_vector_type(4)));
typedef __bf16 bf16x8 __attribute__((ext_vector_type(8)));

__device__ inline short f2bs(float f) {
  unsigned u = __builtin_bit_cast(unsigned, f);
  u += 0x7fffu + ((u >> 16) & 1u);
  return (short)(u >> 16);
}

__device__ inline float bs2f(short s) {
  unsigned u = ((unsigned)(unsigned short)s) << 16;
  return __builtin_bit_cast(float, u);
}

__device__ inline f32x4 mfma16(short8 a, short8 b, f32x4 c) {
  return __builtin_amdgcn_mfma_f32_16x16x32_bf16(
      __builtin_bit_cast(bf16x8, a), __builtin_bit_cast(bf16x8, b), c, 0, 0, 0);
}

// ---------------- hypernet small chain (fp32) ----------------
__global__ void k_h0(const float* __restrict__ lat, const float* __restrict__ w,
                     const float* __restrict__ bias, float* __restrict__ h0) {
  int j = blockIdx.x * 256 + threadIdx.x;   // < 512
  int b = blockIdx.y;
  const float* lp = lat + b * 512;
  float acc = bias[j];
#pragma unroll 16
  for (int k = 0; k < 512; ++k) acc = fmaf(lp[k], w[k * 512 + j], acc);
  h0[b * 512 + j] = acc;
}

__global__ void k_t1(const float* __restrict__ h0, const float* __restrict__ w,
                     const float* __restrict__ bias, float* __restrict__ t1) {
  int j = blockIdx.x * 256 + threadIdx.x;   // < 1024
  int b = blockIdx.y;
  const float* hp = h0 + b * 512;
  float acc = bias[j];
#pragma unroll 16
  for (int k = 0; k < 512; ++k) acc = fmaf(hp[k], w[k * 1024 + j], acc);
  t1[b * 1024 + j] = fmaxf(acc, 0.f);
}

__global__ void k_h(const float* __restrict__ h0, const float* __restrict__ t1,
                    const float* __restrict__ w, const float* __restrict__ bias,
                    float* __restrict__ h, float* __restrict__ hx) {
  int j = blockIdx.x * 256 + threadIdx.x;   // < 512
  int b = blockIdx.y;
  const float* tp = t1 + b * 1024;
  float acc = bias[j];
#pragma unroll 16
  for (int k = 0; k < 1024; ++k) acc = fmaf(tp[k], w[k * 512 + j], acc);
  float v = acc + h0[b * 512 + j];
  h[b * 512 + j] = v;
  hx[j * 16 + b] = v;   // rows 0..511 of combined [1536][16]
}

__global__ void k_t2(const float* __restrict__ h, const float* __restrict__ w,
                     const float* __restrict__ bias, float* __restrict__ hx) {
  int j = blockIdx.x * 256 + threadIdx.x;   // < 1024
  int b = blockIdx.y;
  const float* hp = h + b * 512;
  float acc = bias[j];
#pragma unroll 16
  for (int k = 0; k < 512; ++k) acc = fmaf(hp[k], w[k * 1024 + j], acc);
  hx[(512 + j) * 16 + b] = fmaxf(acc, 0.f);  // rows 512..1535
}

// ---------------- fat GEMM: ksv = h @ l2_ws + t2 @ l2_w2 (k-split partials) ----------------
// CHUNK=64 -> every chunk lies fully inside one weight matrix: one uniform
// SGPR base per block, zero per-load selects. Fully-unrolled 8-group software
// pipeline keeps 8 independent dwordx2 weight loads in flight per wave.
#define KSTEP(kt, wv) { \
    const f32x4* hp_ = reinterpret_cast<const f32x4*>(hs + (kt) * 16); \
    f32x4 h0v = hp_[0], h1v = hp_[1], h2v = hp_[2], h3v = hp_[3]; \
    _Pragma("unroll") \
    for (int q = 0; q < 4; ++q) { \
      acc[q]      += h0v[q] * (wv); \
      acc[4 + q]  += h1v[q] * (wv); \
      acc[8 + q]  += h2v[q] * (wv); \
      acc[12 + q] += h3v[q] * (wv); \
    } }

__global__ __launch_bounds__(256) void k5_partial(
    const float* __restrict__ wsm, const float* __restrict__ w2,
    const float* __restrict__ hx, short* __restrict__ part) {
  __shared__ float hs[CHUNK * 16];
  const int tid = threadIdx.x;
  const int chunk = blockIdx.y;
  const int k0 = chunk * CHUNK;

  // stage hx[k0..k0+CHUNK) -> LDS (coalesced float4; broadcast-read later)
  {
    const f32x4* src = reinterpret_cast<const f32x4*>(hx + (size_t)k0 * 16);
    f32x4* dst = reinterpret_cast<f32x4*>(hs);
    for (int idx = tid; idx < CHUNK * 4; idx += 256) dst[idx] = src[idx];
  }
  __syncthreads();

  const int j0 = (blockIdx.x * 256 + tid) * 2;
  if (j0 >= N_KSV) return;

  f32x2 acc[16];
#pragma unroll
  for (int b = 0; b < 16; ++b) acc[b] = (f32x2){0.f, 0.f};

  // uniform per-block weight base (chunk 0..7 -> l2_ws rows, 8..23 -> l2_w2 rows)
  const float* wrow = (chunk < 8) ? (wsm + (size_t)k0 * N_KSV)
                                  : (w2 + (size_t)(k0 - 512) * N_KSV);
  wrow += j0;
#define WROW(kk) (*reinterpret_cast<const f32x2*>(wrow + (size_t)(kk) * N_KSV))

  f32x2 wbuf[8];
#pragma unroll
  for (int i = 0; i < 8; ++i) wbuf[i] = WROW(i);

#pragma unroll
  for (int g = 0; g < 8; ++g) {
    f32x2 wn[8];
    if (g < 7) {
#pragma unroll
      for (int i = 0; i < 8; ++i) wn[i] = WROW(g * 8 + 8 + i);
    }
#pragma unroll
    for (int i = 0; i < 8; ++i) KSTEP(g * 8 + i, wbuf[i]);
    if (g < 7) {
#pragma unroll
      for (int i = 0; i < 8; ++i) wbuf[i] = wn[i];
    }
  }
#undef WROW

  short* pp = part + (size_t)chunk * 16 * N_KSV + j0;
#pragma unroll
  for (int b = 0; b < 16; ++b) {
    int pk = (int)(unsigned short)f2bs(acc[b][0]) | ((int)f2bs(acc[b][1]) << 16);
    *reinterpret_cast<int*>(pp + (size_t)b * N_KSV) = pk;
  }
}

__global__ void k6_reduce(const short* __restrict__ part, const float* __restrict__ b2,
                          float* __restrict__ ksv, short* __restrict__ kwb) {
  int j0 = (blockIdx.x * 256 + threadIdx.x) * 4;
  if (j0 >= N_KSV) return;
  int b = blockIdx.y;
  f32x4 s = *reinterpret_cast<const f32x4*>(b2 + j0);
#pragma unroll 4
  for (int c = 0; c < KSPLIT; ++c) {
    short4v pv = *reinterpret_cast<const short4v*>(part + (size_t)(c * 16 + b) * N_KSV + j0);
#pragma unroll
    for (int q = 0; q < 4; ++q) s[q] += bs2f(pv[q]);
  }
  *reinterpret_cast<f32x4*>(ksv + (size_t)b * N_KSV + j0) = s;
  if (j0 < N_KW) {
    short4v sv;
#pragma unroll
    for (int q = 0; q < 4; ++q) sv[q] = f2bs(s[q]);
    *reinterpret_cast<short4v*>(kwb + (size_t)b * N_KW + j0) = sv;
  }
}

// ---------------- fused dyna block: 4 x (1x1 conv) via bf16 MFMA ----------------
__device__ inline int xT_idx(int p, int c) {
  return p * 64 + ((((c >> 3) ^ (p & 7)) << 3) | (c & 7));
}
__device__ inline int h_idx(int p, int c) {
  return p * 128 + ((((c >> 3) ^ (p & 7)) << 3) | (c & 7));
}

__global__ __launch_bounds__(256) void k_dyna(const float* __restrict__ x,
                                              const short* __restrict__ kwb,
                                              const float* __restrict__ ksv,
                                              float* __restrict__ out) {
  __shared__ __align__(16) short lds[20480];  // xT:0..4095  h1:4096..12287  h2:12288..20479
  short* xT = lds;
  short* h1 = lds + 4096;
  short* h2 = lds + 12288;

  const int tid = threadIdx.x;
  const int lane = tid & 63;
  const int w = tid >> 6;        // wave 0..3
  const int l15 = lane & 15;
  const int lg = lane >> 4;      // 0..3

  const int b = blockIdx.x >> 8;
  const int pos0 = (blockIdx.x & 255) << 6;

  const float* xb = x + ((size_t)b << 20) + pos0;           // x[b][.][pos0+.]
  const short* kw = kwb + b * N_KW;
  const float* bias = ksv + (size_t)b * N_KSV + N_KW;       // b_in | b_mid | b_out | b_sh

  // ---- stage x tile -> xT (bf16, transposed, swizzled) ----
#pragma unroll
  for (int i = 0; i < 8; ++i) {
    int p = lane;
    int cp = i * 4 + w;          // 0..31
    int c = cp * 2;
    float v0 = xb[(size_t)c * 16384 + p];
    float v1 = xb[(size_t)(c + 1) * 16384 + p];
    int idx = xT_idx(p, c);      // even; packs c, c+1
    int pk = (int)(unsigned short)f2bs(v0) | ((int)f2bs(v1) << 16);
    *reinterpret_cast<int*>(&xT[idx]) = pk;
  }
  __syncthreads();

  // ---- layer 1: h1 = relu(Kin(128x64) @ x + b_in) ----
  short8 a1[2][2];
#pragma unroll
  for (int mt = 0; mt < 2; ++mt)
#pragma unroll
    for (int kf = 0; kf < 2; ++kf)
      a1[mt][kf] = *reinterpret_cast<const short8*>(
          kw + (w * 32 + mt * 16 + l15) * 64 + kf * 32 + lg * 8);

  f32x4 zero = {0.f, 0.f, 0.f, 0.f};
  f32x4 acc1[2][4];
#pragma unroll
  for (int mt = 0; mt < 2; ++mt)
#pragma unroll
    for (int nt = 0; nt < 4; ++nt) acc1[mt][nt] = zero;

#pragma unroll
  for (int nt = 0; nt < 4; ++nt) {
    int p = nt * 16 + l15;
    short8 b0 = *reinterpret_cast<const short8*>(&xT[xT_idx(p, lg * 8)]);
    short8 b1 = *reinterpret_cast<const short8*>(&xT[xT_idx(p, 32 + lg * 8)]);
#pragma unroll
    for (int mt = 0; mt < 2; ++mt) {
      acc1[mt][nt] = mfma16(a1[mt][0], b0, acc1[mt][nt]);
      acc1[mt][nt] = mfma16(a1[mt][1], b1, acc1[mt][nt]);
    }
  }
#pragma unroll
  for (int mt = 0; mt < 2; ++mt) {
    int ch0 = w * 32 + mt * 16 + lg * 4;
    f32x4 bv = *reinterpret_cast<const f32x4*>(bias + ch0);
#pragma unroll
    for (int nt = 0; nt < 4; ++nt) {
      int p = nt * 16 + l15;
      short4v hv;
#pragma unroll
      for (int jj = 0; jj < 4; ++jj)
        hv[jj] = f2bs(fmaxf(acc1[mt][nt][jj] + bv[jj], 0.f));
      *reinterpret_cast<short4v*>(&h1[h_idx(p, ch0)]) = hv;
    }
  }
  __syncthreads();

  // ---- layer 2: h2 = relu(Kmid(128x128) @ h1 + b_mid) ----
  short8 a2[2][4];
#pragma unroll
  for (int mt = 0; mt < 2; ++mt)
#pragma unroll
    for (int kf = 0; kf < 4; ++kf)
      a2[mt][kf] = *reinterpret_cast<const short8*>(
          kw + 8192 + (w * 32 + mt * 16 + l15) * 128 + kf * 32 + lg * 8);

  f32x4 acc2[2][4];
#pragma unroll
  for (int mt = 0; mt < 2; ++mt)
#pragma unroll
    for (int nt = 0; nt < 4; ++nt) acc2[mt][nt] = zero;

#pragma unroll
  for (int nt = 0; nt < 4; ++nt) {
    int p = nt * 16 + l15;
    short8 bb[4];
#pragma unroll
    for (int kf = 0; kf < 4; ++kf)
      bb[kf] = *reinterpret_cast<const short8*>(&h1[h_idx(p, kf * 32 + lg * 8)]);
#pragma unroll
    for (int mt = 0; mt < 2; ++mt)
#pragma unroll
      for (int kf = 0; kf < 4; ++kf)
        acc2[mt][nt] = mfma16(a2[mt][kf], bb[kf], acc2[mt][nt]);
  }
#pragma unroll
  for (int mt = 0; mt < 2; ++mt) {
    int ch0 = w * 32 + mt * 16 + lg * 4;
    f32x4 bv = *reinterpret_cast<const f32x4*>(bias + 128 + ch0);
#pragma unroll
    for (int nt = 0; nt < 4; ++nt) {
      int p = nt * 16 + l15;
      short4v hv;
#pragma unroll
      for (int jj = 0; jj < 4; ++jj)
        hv[jj] = f2bs(fmaxf(acc2[mt][nt][jj] + bv[jj], 0.f));
      *reinterpret_cast<short4v*>(&h2[h_idx(p, ch0)]) = hv;
    }
  }
  __syncthreads();

  // ---- layer 3: out = Kout(64x128) @ h2 + Ksh(64x64) @ x + b_out + b_sh ----
  short8 a3[4], ash[2];
#pragma unroll
  for (int kf = 0; kf < 4; ++kf)
    a3[kf] = *reinterpret_cast<const short8*>(
        kw + 24576 + (w * 16 + l15) * 128 + kf * 32 + lg * 8);
#pragma unroll
  for (int kf = 0; kf < 2; ++kf)
    ash[kf] = *reinterpret_cast<const short8*>(
        kw + 32768 + (w * 16 + l15) * 64 + kf * 32 + lg * 8);

  int ch0 = w * 16 + lg * 4;
  f32x4 bo = *reinterpret_cast<const f32x4*>(bias + 256 + ch0);
  f32x4 bs = *reinterpret_cast<const f32x4*>(bias + 320 + ch0);

#pragma unroll
  for (int nt = 0; nt < 4; ++nt) {
    int p = nt * 16 + l15;
    f32x4 acc = zero;
#pragma unroll
    for (int kf = 0; kf < 4; ++kf) {
      short8 bb = *reinterpret_cast<const short8*>(&h2[h_idx(p, kf * 32 + lg * 8)]);
      acc = mfma16(a3[kf], bb, acc);
    }
#pragma unroll
    for (int kf = 0; kf < 2; ++kf) {
      short8 bb = *reinterpret_cast<const short8*>(&xT[xT_idx(p, kf * 32 + lg * 8)]);
      acc = mfma16(ash[kf], bb, acc);
    }
#pragma unroll
    for (int jj = 0; jj < 4; ++jj)
      out[((size_t)(b * 64 + ch0 + jj) << 14) + pos0 + p] = acc[jj] + bo[jj] + bs[jj];
  }
}

extern "C" void kernel_launch(void* const* d_in, const int* in_sizes, int n_in,
                              void* d_out, int out_size, void* d_ws, size_t ws_size,
                              hipStream_t stream) {
  const float* x    = (const float*)d_in[0];
  const float* lat  = (const float*)d_in[1];
  const float* dk_w = (const float*)d_in[2];
  const float* dk_b = (const float*)d_in[3];
  const float* l1w1 = (const float*)d_in[4];
  const float* l1b1 = (const float*)d_in[5];
  const float* l1w2 = (const float*)d_in[6];
  const float* l1b2 = (const float*)d_in[7];
  const float* l2w1 = (const float*)d_in[8];
  const float* l2b1 = (const float*)d_in[9];
  const float* l2w2 = (const float*)d_in[10];
  const float* l2b2 = (const float*)d_in[11];
  const float* l2ws = (const float*)d_in[12];
  float* out = (float*)d_out;
  float* wsf = (float*)d_ws;

  float* h0  = wsf;                  // 8192
  float* t1  = wsf + 8192;           // 16384
  float* h   = wsf + 24576;          // 8192
  float* hx  = wsf + 32768;          // 24576  ([1536][16] combined h|t2)
  float* ksv = wsf + 57344;          // 595968
  short* part = (short*)(wsf + 653312);          // KSPLIT*16*N_KSV bf16
  short* kwb  = part + (size_t)KSPLIT * 16 * N_KSV;

  k_h0<<<dim3(2, 16), 256, 0, stream>>>(lat, dk_w, dk_b, h0);
  k_t1<<<dim3(4, 16), 256, 0, stream>>>(h0, l1w1, l1b1, t1);
  k_h <<<dim3(2, 16), 256, 0, stream>>>(h0, t1, l1w2, l1b2, h, hx);
  k_t2<<<dim3(4, 16), 256, 0, stream>>>(h, l2w1, l2b1, hx);
  k5_partial<<<dim3((N_KSV / 2 + 255) / 256, KSPLIT), 256, 0, stream>>>(l2ws, l2w2, hx, part);
  k6_reduce<<<dim3((N_KSV / 4 + 255) / 256, 16), 256, 0, stream>>>(part, l2b2, ksv, kwb);
  k_dyna<<<dim3(4096), 256, 0, stream>>>(x, kwb, ksv, out);
}